// Round 8
// baseline (637.348 us; speedup 1.0000x reference)
//
#include <hip/hip_runtime.h>
#include <hip/hip_bf16.h>

// Model_39676907885326: out = softmax(causal(q)) @ e
//   e[i,j,l]  = sum_k in[i,j,k] * w[l,k,j]
//   attn[i,j,l] = softmax_{l<=j}( (sum_k in[i,j,k]) * w[i,j,l] / (0.5 + sum_l w[i,j,l]) )
//   out[i]    = attn[i] @ e[i]
//
// Pipeline (ws = 2 regions of N^3 bf16):
//   R0 [0, N3) bf16   : wt[j][l][k]  ->  et[i][l][m]
//   R1 [N3, 2*N3) bf16: e[i][j][l]   ->  attn[i][j][m]  (attn written by k_e2f)
//   kT -> k_e2f (GEMM + fused attn rows in l0==0 blocks) -> k_eT -> k_av2
//
// R8: r5 GEMM structure restored (r6 dbuf and r7 serial-fusion both lost).
// k_attn folded into k_e2f's l0==0 blocks as post-epilogue independent work:
// it overlaps other blocks' staging stalls instead of a dedicated pass.

#define N 384
#define N2 (N * N)
#define BK 64
static const size_t N3 = (size_t)N * N * N;

typedef __attribute__((ext_vector_type(8))) short s16x8;
typedef __attribute__((ext_vector_type(4))) float f32x4;

#define AS1 __attribute__((address_space(1)))
#define AS3 __attribute__((address_space(3)))
__device__ __forceinline__ void gll16(const void* g, void* l) {
    __builtin_amdgcn_global_load_lds((const AS1 unsigned int*)g,
                                     (AS3 unsigned int*)l, 16, 0, 0);
}

__device__ __forceinline__ unsigned short f32_to_bf16(float f) {
    unsigned int u = __float_as_uint(f);
    u += 0x7FFFu + ((u >> 16) & 1u);
    return (unsigned short)(u >> 16);
}
__device__ __forceinline__ unsigned int pk2(float a, float b) {
    return (unsigned int)f32_to_bf16(a) | ((unsigned int)f32_to_bf16(b) << 16);
}

// ---------------------------------------------------------------------------
// kT: wt[j*N2 + r] = bf16(w[r*N + j]), r = l*N+k
// ---------------------------------------------------------------------------
__global__ __launch_bounds__(256) void kT(const float* __restrict__ w,
                                          unsigned short* __restrict__ wt) {
    __shared__ unsigned short tile[64][68];
    const int r0 = blockIdx.x * 64;
    const int j0 = blockIdx.y * 64;
    const int tx = threadIdx.x & 63;
    const int ty = threadIdx.x >> 6;
#pragma unroll
    for (int p = 0; p < 16; ++p) {
        const int r = ty * 16 + p;
        tile[r][tx] = f32_to_bf16(w[(size_t)(r0 + r) * N + j0 + tx]);
    }
    __syncthreads();
#pragma unroll
    for (int p = 0; p < 16; ++p) {
        const int jj = ty * 16 + p;
        wt[(size_t)(j0 + jj) * N2 + r0 + tx] = tile[tx][jj];
    }
}

// ---------------------------------------------------------------------------
// k_e2f: per j: e[i0..i0+63, j, l0..l0+191] = in[i,j,:] . wt[j][l][:]
// r5 structure (single-buffer 32KB, va reg prefetch, gll B).
// l0==0 blocks additionally compute the 64 attn rows (i0..i0+63, j) after
// the epilogue, using the in-register rsum (no rs array, no extra pass).
// ---------------------------------------------------------------------------
__global__ __launch_bounds__(256, 4) void k_e2f(const float* __restrict__ in,
                                                const float* __restrict__ w,
                                                const unsigned short* __restrict__ wt,
                                                unsigned short* __restrict__ e,
                                                unsigned short* __restrict__ attn) {
    __shared__ union {
        struct { unsigned short A[64 * 64]; unsigned short B[192 * 64]; } s;
        unsigned short C[64 * 200];
    } sm;

    const int lin = blockIdx.x;               // 4608 = 8 * 576
    const int swz = (lin & 7) * 576 + (lin >> 3);
    const int j   = swz / 12;
    const int sub = swz % 12;
    const int i0  = (sub >> 1) * 64;
    const int l0  = (sub & 1) * 192;

    const int t = threadIdx.x, lane = t & 63, wv = t >> 6;
    const int fr = lane & 15, fx = lane >> 4;

    const int ra = t >> 2, ca = (t & 3) * 2;
    const float* Ab = in + (size_t)(i0 + ra) * N2 + (size_t)j * N + ca * 8;
    unsigned short* AsW0 = sm.s.A + ra * 64 + (((ca + 0) ^ (ra & 7)) * 8);
    unsigned short* AsW1 = sm.s.A + ra * 64 + (((ca + 1) ^ (ra & 7)) * 8);

    const unsigned short* Wj = wt + (size_t)j * N2 + (size_t)l0 * N;
    const int rb_off = lane >> 3;
    const int p8     = lane & 7;

    f32x4 acc[4][3];
#pragma unroll
    for (int m = 0; m < 4; ++m)
#pragma unroll
        for (int n = 0; n < 3; ++n) acc[m][n] = (f32x4){0.f, 0.f, 0.f, 0.f};

    float rsum = 0.f;

    float4 va[4];
    va[0] = *(const float4*)(Ab);
    va[1] = *(const float4*)(Ab + 4);
    va[2] = *(const float4*)(Ab + 8);
    va[3] = *(const float4*)(Ab + 12);

    for (int k0 = 0; k0 < N; k0 += BK) {
        __syncthreads();
        {
            rsum += (va[0].x + va[0].y + va[0].z + va[0].w) +
                    (va[1].x + va[1].y + va[1].z + va[1].w) +
                    (va[2].x + va[2].y + va[2].z + va[2].w) +
                    (va[3].x + va[3].y + va[3].z + va[3].w);
            uint4 a0, a1;
            a0.x = pk2(va[0].x, va[0].y); a0.y = pk2(va[0].z, va[0].w);
            a0.z = pk2(va[1].x, va[1].y); a0.w = pk2(va[1].z, va[1].w);
            a1.x = pk2(va[2].x, va[2].y); a1.y = pk2(va[2].z, va[2].w);
            a1.z = pk2(va[3].x, va[3].y); a1.w = pk2(va[3].z, va[3].w);
            *(uint4*)AsW0 = a0;
            *(uint4*)AsW1 = a1;
        }
#pragma unroll
        for (int itb = 0; itb < 6; ++itb) {
            const int rb = wv * 48 + itb * 8 + rb_off;
            const int sc = p8 ^ (rb & 7);
            gll16(Wj + (size_t)rb * N + k0 + sc * 8,
                  sm.s.B + (wv * 48 + itb * 8) * 64);
        }
        if (k0 + BK < N) {
            const float* An = Ab + k0 + BK;
            va[0] = *(const float4*)(An);
            va[1] = *(const float4*)(An + 4);
            va[2] = *(const float4*)(An + 8);
            va[3] = *(const float4*)(An + 12);
        }
        __syncthreads();
#pragma unroll
        for (int kk = 0; kk < 2; ++kk) {
            s16x8 af[4], bf[3];
#pragma unroll
            for (int m = 0; m < 4; ++m) {
                const int row = m * 16 + fr;
                const int x   = (kk * 4 + fx) ^ (row & 7);
                af[m] = *(const s16x8*)(sm.s.A + row * 64 + x * 8);
            }
#pragma unroll
            for (int n = 0; n < 3; ++n) {
                const int row = wv * 48 + n * 16 + fr;
                const int x   = (kk * 4 + fx) ^ (row & 7);
                bf[n] = *(const s16x8*)(sm.s.B + row * 64 + x * 8);
            }
#pragma unroll
            for (int m = 0; m < 4; ++m)
#pragma unroll
                for (int n = 0; n < 3; ++n)
                    acc[m][n] = __builtin_amdgcn_mfma_f32_16x16x32_bf16(
                        af[m], bf[n], acc[m][n], 0, 0, 0);
        }
    }

    // row-sum of in[i0+ra, j, :] shared by the 4 threads of the row
    rsum += __shfl_xor(rsum, 1, 64);
    rsum += __shfl_xor(rsum, 2, 64);

    // epilogue: assemble 64x192 bf16 in LDS, stream full lines
    __syncthreads();
#pragma unroll
    for (int m = 0; m < 4; ++m)
#pragma unroll
        for (int n = 0; n < 3; ++n)
#pragma unroll
            for (int r = 0; r < 4; ++r)
                sm.C[(m * 16 + fx * 4 + r) * 200 + wv * 48 + n * 16 + fr] =
                    f32_to_bf16(acc[m][n][r]);
    __syncthreads();
#pragma unroll
    for (int it = 0; it < 6; ++it) {
        const int cid = it * 256 + t;
        const int row = cid / 24;
        const int c   = cid % 24;
        *(uint4*)(e + (size_t)(i0 + row) * N2 + (size_t)j * N + l0 + c * 8) =
            *(const uint4*)&sm.C[row * 200 + c * 8];
    }

    // ---- fused attn rows (l0==0 blocks only): rows (i0+ra, j) ----
    if (l0 == 0) {
        const int q0 = t & 3;                              // col quarter
        const float* Wrow = w + ((size_t)(i0 + ra) * N + j) * N;

        // sweep 1: full-row sum + causal max (l <= j)
        float s_w = 0.f, mx = -INFINITY;
#pragma unroll
        for (int c = 0; c < 24; ++c) {
            const int col = q0 * 4 + c * 16;
            float4 v = *(const float4*)(Wrow + col);
            s_w += v.x + v.y + v.z + v.w;
            float m0 = (col + 0 <= j) ? v.x : -INFINITY;
            float m1 = (col + 1 <= j) ? v.y : -INFINITY;
            float m2 = (col + 2 <= j) ? v.z : -INFINITY;
            float m3 = (col + 3 <= j) ? v.w : -INFINITY;
            mx = fmaxf(mx, fmaxf(fmaxf(m0, m1), fmaxf(m2, m3)));
        }
        s_w += __shfl_xor(s_w, 1, 64);
        s_w += __shfl_xor(s_w, 2, 64);
        mx = fmaxf(mx, __shfl_xor(mx, 1, 64));
        mx = fmaxf(mx, __shfl_xor(mx, 2, 64));

        const float aa = (rsum / (0.5f + s_w)) * 1.44269504f;  // scale*log2e, >0

        // sweep 2 (L2-hot): exp-sum
        float s_e = 0.f;
#pragma unroll
        for (int c = 0; c < 24; ++c) {
            const int col = q0 * 4 + c * 16;
            float4 v = *(const float4*)(Wrow + col);
            float e0 = (col + 0 <= j) ? exp2f(aa * (v.x - mx)) : 0.f;
            float e1 = (col + 1 <= j) ? exp2f(aa * (v.y - mx)) : 0.f;
            float e2 = (col + 2 <= j) ? exp2f(aa * (v.z - mx)) : 0.f;
            float e3 = (col + 3 <= j) ? exp2f(aa * (v.w - mx)) : 0.f;
            s_e += e0 + e1 + e2 + e3;
        }
        s_e += __shfl_xor(s_e, 1, 64);
        s_e += __shfl_xor(s_e, 2, 64);
        const float inv = 1.f / s_e;

        // sweep 3 (L2-hot): write normalized P row (bf16)
        unsigned int* Arow = (unsigned int*)(attn + ((size_t)(i0 + ra) * N + j) * N);
#pragma unroll
        for (int c = 0; c < 24; ++c) {
            const int col = q0 * 4 + c * 16;
            float4 v = *(const float4*)(Wrow + col);
            float p0 = (col + 0 <= j) ? exp2f(aa * (v.x - mx)) * inv : 0.f;
            float p1 = (col + 1 <= j) ? exp2f(aa * (v.y - mx)) * inv : 0.f;
            float p2 = (col + 2 <= j) ? exp2f(aa * (v.z - mx)) * inv : 0.f;
            float p3 = (col + 3 <= j) ? exp2f(aa * (v.w - mx)) * inv : 0.f;
            Arow[col / 2]     = pk2(p0, p1);
            Arow[col / 2 + 1] = pk2(p2, p3);
        }
    }
}

// ---------------------------------------------------------------------------
// k_eT: et[i][l][m] = e[i][m][l]
// ---------------------------------------------------------------------------
__global__ __launch_bounds__(256) void k_eT(const unsigned short* __restrict__ e,
                                            unsigned short* __restrict__ et) {
    __shared__ unsigned short tile[64][68];
    const int m0 = blockIdx.x * 64, l0 = blockIdx.y * 64;
    const size_t ib = (size_t)blockIdx.z * N2;
    const int t  = threadIdx.x;
    const int c4 = (t & 15) * 4, r = t >> 4;
#pragma unroll
    for (int p = 0; p < 4; ++p) {
        ushort4 v = *(const ushort4*)(e + ib + (size_t)(m0 + r + 16 * p) * N + l0 + c4);
        tile[c4 + 0][r + 16 * p] = v.x;
        tile[c4 + 1][r + 16 * p] = v.y;
        tile[c4 + 2][r + 16 * p] = v.z;
        tile[c4 + 3][r + 16 * p] = v.w;
    }
    __syncthreads();
#pragma unroll
    for (int p = 0; p < 4; ++p) {
        const int lr = r + 16 * p;
        ushort4 v = *(const ushort4*)&tile[lr][c4];
        *(ushort4*)(et + ib + (size_t)(l0 + lr) * N + m0 + c4) = v;
    }
}

// ---------------------------------------------------------------------------
// k_av2: per i: out[j0..j0+63, l0..l0+191] = attn[i] @ et[i]^T, K <= j0+64
// (r5 structure: single-buffer, gll A+B staging)
// ---------------------------------------------------------------------------
__global__ __launch_bounds__(256, 4) void k_av2(const unsigned short* __restrict__ attn,
                                                const unsigned short* __restrict__ et,
                                                float* __restrict__ out) {
    __shared__ union {
        struct { unsigned short A[64 * 64]; unsigned short B[192 * 64]; } s;
        float C[32 * 196];
    } sm;

    const int lin = blockIdx.x;
    const int swz = (lin & 7) * 576 + (lin >> 3);
    const int i   = swz / 12;
    const int sub = swz % 12;
    const int j0  = (sub >> 1) * 64;
    const int l0  = (sub & 1) * 192;
    const int kmax = j0 + 64;

    const int t = threadIdx.x, lane = t & 63, wv = t >> 6;
    const int fr = lane & 15, fx = lane >> 4;
    const int rb_off = lane >> 3;
    const int p8     = lane & 7;

    const unsigned short* Ag = attn + (size_t)i * N2 + (size_t)j0 * N;
    const unsigned short* Bg = et + (size_t)i * N2 + (size_t)l0 * N;

    f32x4 acc[4][3];
#pragma unroll
    for (int m = 0; m < 4; ++m)
#pragma unroll
        for (int n = 0; n < 3; ++n) acc[m][n] = (f32x4){0.f, 0.f, 0.f, 0.f};

    for (int k0 = 0; k0 < kmax; k0 += BK) {
        __syncthreads();
#pragma unroll
        for (int ita = 0; ita < 2; ++ita) {
            const int rb = wv * 16 + ita * 8 + rb_off;
            const int sc = p8 ^ (rb & 7);
            gll16(Ag + (size_t)rb * N + k0 + sc * 8,
                  sm.s.A + (wv * 16 + ita * 8) * 64);
        }
#pragma unroll
        for (int itb = 0; itb < 6; ++itb) {
            const int rb = wv * 48 + itb * 8 + rb_off;
            const int sc = p8 ^ (rb & 7);
            gll16(Bg + (size_t)rb * N + k0 + sc * 8,
                  sm.s.B + (wv * 48 + itb * 8) * 64);
        }
        __syncthreads();
#pragma unroll
        for (int kk = 0; kk < 2; ++kk) {
            s16x8 af[4], bf[3];
#pragma unroll
            for (int m = 0; m < 4; ++m) {
                const int row = m * 16 + fr;
                const int x   = (kk * 4 + fx) ^ (row & 7);
                af[m] = *(const s16x8*)(sm.s.A + row * 64 + x * 8);
            }
#pragma unroll
            for (int n = 0; n < 3; ++n) {
                const int row = wv * 48 + n * 16 + fr;
                const int x   = (kk * 4 + fx) ^ (row & 7);
                bf[n] = *(const s16x8*)(sm.s.B + row * 64 + x * 8);
            }
#pragma unroll
            for (int m = 0; m < 4; ++m)
#pragma unroll
                for (int n = 0; n < 3; ++n)
                    acc[m][n] = __builtin_amdgcn_mfma_f32_16x16x32_bf16(
                        af[m], bf[n], acc[m][n], 0, 0, 0);
        }
    }

    __syncthreads();
#pragma unroll
    for (int ph = 0; ph < 2; ++ph) {
#pragma unroll
        for (int mm = 0; mm < 2; ++mm)
#pragma unroll
            for (int n = 0; n < 3; ++n)
#pragma unroll
                for (int r = 0; r < 4; ++r)
                    sm.C[(mm * 16 + fx * 4 + r) * 196 + wv * 48 + n * 16 + fr] =
                        acc[ph * 2 + mm][n][r];
        __syncthreads();
#pragma unroll
        for (int it = 0; it < 6; ++it) {
            const int cid = it * 256 + t;
            const int row = cid / 48;
            const int c   = cid % 48;
            *(float4*)(out + (size_t)i * N2 + (size_t)(j0 + ph * 32 + row) * N + l0 + c * 4) =
                *(const float4*)&sm.C[row * 196 + c * 4];
        }
        if (ph == 0) __syncthreads();
    }
}

extern "C" void kernel_launch(void* const* d_in, const int* in_sizes, int n_in,
                              void* d_out, int out_size, void* d_ws, size_t ws_size,
                              hipStream_t stream) {
    const float* in = (const float*)d_in[0];
    const float* w  = (const float*)d_in[1];
    float* out      = (float*)d_out;

    unsigned short* r0 = (unsigned short*)d_ws;       // wt -> et
    unsigned short* r1 = (unsigned short*)d_ws + N3;  // e  -> attn (attn in R1? no:)
    // attn lives in R1 only AFTER e has been consumed by k_eT. But k_e2f
    // writes attn DURING the e pass — so attn needs its own region:
    unsigned short* attn = (unsigned short*)d_ws + 2 * N3;  // third region

    kT<<<dim3(N2 / 64, N / 64), 256, 0, stream>>>(w, r0);
    k_e2f<<<dim3(4608), 256, 0, stream>>>(in, w, r0, r1, attn);
    k_eT<<<dim3(6, 6, N), 256, 0, stream>>>(r1, r0);
    k_av2<<<dim3(4608), 256, 0, stream>>>(attn, r0, out);
}

// Round 9
// 393.972 us; speedup vs baseline: 1.6178x; 1.6178x over previous
//
#include <hip/hip_runtime.h>
#include <hip/hip_bf16.h>

// Model_39676907885326: out = softmax(causal(q)) @ e
//   e[i,j,l]  = sum_k in[i,j,k] * w[l,k,j]
//   attn[i,j,l] = softmax_{l<=j}( (sum_k in[i,j,k]) * w[i,j,l] / (0.5 + sum_l w[i,j,l]) )
//   out[i]    = attn[i] @ e[i]
//
// Pipeline (ws regions):
//   R0 [0, N3) bf16        : wt[j][l][k]  ->  et[i][l][m]
//   R1 [N3, 2*N3) bf16     : e[i][j][l]   ->  attn[i][j][m]
//   RS [2*N3 ..) fp32 N2   : rs[i][j] = sum_k in[i,j,k]   (written by k_e2)
//   kT -> k_e2(+rs) -> k_eT -> k_attn(rs) -> k_av128
//
// R9: full revert to the r5 structure (best measured: 398 us). Single change:
// k_av2 (64x192 tile) -> k_av128 (128x128 tile, all-gll, 32 MFMA/wave/step
// per barrier-drain vs 24) to attack the barrier-latency gap.

#define N 384
#define N2 (N * N)
#define BK 64
static const size_t N3 = (size_t)N * N * N;

typedef __attribute__((ext_vector_type(8))) short s16x8;
typedef __attribute__((ext_vector_type(4))) float f32x4;

#define AS1 __attribute__((address_space(1)))
#define AS3 __attribute__((address_space(3)))
__device__ __forceinline__ void gll16(const void* g, void* l) {
    __builtin_amdgcn_global_load_lds((const AS1 unsigned int*)g,
                                     (AS3 unsigned int*)l, 16, 0, 0);
}

__device__ __forceinline__ unsigned short f32_to_bf16(float f) {
    unsigned int u = __float_as_uint(f);
    u += 0x7FFFu + ((u >> 16) & 1u);
    return (unsigned short)(u >> 16);
}
__device__ __forceinline__ unsigned int pk2(float a, float b) {
    return (unsigned int)f32_to_bf16(a) | ((unsigned int)f32_to_bf16(b) << 16);
}

// ---------------------------------------------------------------------------
// kT: wt[j*N2 + r] = bf16(w[r*N + j]), r = l*N+k
// ---------------------------------------------------------------------------
__global__ __launch_bounds__(256) void kT(const float* __restrict__ w,
                                          unsigned short* __restrict__ wt) {
    __shared__ unsigned short tile[64][68];
    const int r0 = blockIdx.x * 64;
    const int j0 = blockIdx.y * 64;
    const int tx = threadIdx.x & 63;
    const int ty = threadIdx.x >> 6;
#pragma unroll
    for (int p = 0; p < 16; ++p) {
        const int r = ty * 16 + p;
        tile[r][tx] = f32_to_bf16(w[(size_t)(r0 + r) * N + j0 + tx]);
    }
    __syncthreads();
#pragma unroll
    for (int p = 0; p < 16; ++p) {
        const int jj = ty * 16 + p;
        wt[(size_t)(j0 + jj) * N2 + r0 + tx] = tile[tx][jj];
    }
}

// ---------------------------------------------------------------------------
// k_e2: per j: e[i0..i0+63, j, l0..l0+191] = in[i,j,:] . wt[j][l][:]
// r5 structure: single-buffer 32KB LDS, va register prefetch, gll B.
// ---------------------------------------------------------------------------
__global__ __launch_bounds__(256, 4) void k_e2(const float* __restrict__ in,
                                               const unsigned short* __restrict__ wt,
                                               unsigned short* __restrict__ e,
                                               float* __restrict__ rs) {
    __shared__ union {
        struct { unsigned short A[64 * 64]; unsigned short B[192 * 64]; } s;
        unsigned short C[64 * 200];
    } sm;

    const int lin = blockIdx.x;               // 4608 = 8 * 576
    const int swz = (lin & 7) * 576 + (lin >> 3);
    const int j   = swz / 12;
    const int sub = swz % 12;
    const int i0  = (sub >> 1) * 64;
    const int l0  = (sub & 1) * 192;

    const int t = threadIdx.x, lane = t & 63, wv = t >> 6;
    const int fr = lane & 15, fx = lane >> 4;

    const int ra = t >> 2, ca = (t & 3) * 2;
    const float* Ab = in + (size_t)(i0 + ra) * N2 + (size_t)j * N + ca * 8;
    unsigned short* AsW0 = sm.s.A + ra * 64 + (((ca + 0) ^ (ra & 7)) * 8);
    unsigned short* AsW1 = sm.s.A + ra * 64 + (((ca + 1) ^ (ra & 7)) * 8);

    const unsigned short* Wj = wt + (size_t)j * N2 + (size_t)l0 * N;
    const int rb_off = lane >> 3;
    const int p8     = lane & 7;

    f32x4 acc[4][3];
#pragma unroll
    for (int m = 0; m < 4; ++m)
#pragma unroll
        for (int n = 0; n < 3; ++n) acc[m][n] = (f32x4){0.f, 0.f, 0.f, 0.f};

    float rsum = 0.f;

    float4 va[4];
    va[0] = *(const float4*)(Ab);
    va[1] = *(const float4*)(Ab + 4);
    va[2] = *(const float4*)(Ab + 8);
    va[3] = *(const float4*)(Ab + 12);

    for (int k0 = 0; k0 < N; k0 += BK) {
        __syncthreads();
        {
            rsum += (va[0].x + va[0].y + va[0].z + va[0].w) +
                    (va[1].x + va[1].y + va[1].z + va[1].w) +
                    (va[2].x + va[2].y + va[2].z + va[2].w) +
                    (va[3].x + va[3].y + va[3].z + va[3].w);
            uint4 a0, a1;
            a0.x = pk2(va[0].x, va[0].y); a0.y = pk2(va[0].z, va[0].w);
            a0.z = pk2(va[1].x, va[1].y); a0.w = pk2(va[1].z, va[1].w);
            a1.x = pk2(va[2].x, va[2].y); a1.y = pk2(va[2].z, va[2].w);
            a1.z = pk2(va[3].x, va[3].y); a1.w = pk2(va[3].z, va[3].w);
            *(uint4*)AsW0 = a0;
            *(uint4*)AsW1 = a1;
        }
#pragma unroll
        for (int itb = 0; itb < 6; ++itb) {
            const int rb = wv * 48 + itb * 8 + rb_off;
            const int sc = p8 ^ (rb & 7);
            gll16(Wj + (size_t)rb * N + k0 + sc * 8,
                  sm.s.B + (wv * 48 + itb * 8) * 64);
        }
        if (k0 + BK < N) {
            const float* An = Ab + k0 + BK;
            va[0] = *(const float4*)(An);
            va[1] = *(const float4*)(An + 4);
            va[2] = *(const float4*)(An + 8);
            va[3] = *(const float4*)(An + 12);
        }
        __syncthreads();
#pragma unroll
        for (int kk = 0; kk < 2; ++kk) {
            s16x8 af[4], bf[3];
#pragma unroll
            for (int m = 0; m < 4; ++m) {
                const int row = m * 16 + fr;
                const int x   = (kk * 4 + fx) ^ (row & 7);
                af[m] = *(const s16x8*)(sm.s.A + row * 64 + x * 8);
            }
#pragma unroll
            for (int n = 0; n < 3; ++n) {
                const int row = wv * 48 + n * 16 + fr;
                const int x   = (kk * 4 + fx) ^ (row & 7);
                bf[n] = *(const s16x8*)(sm.s.B + row * 64 + x * 8);
            }
#pragma unroll
            for (int m = 0; m < 4; ++m)
#pragma unroll
                for (int n = 0; n < 3; ++n)
                    acc[m][n] = __builtin_amdgcn_mfma_f32_16x16x32_bf16(
                        af[m], bf[n], acc[m][n], 0, 0, 0);
        }
    }

    rsum += __shfl_xor(rsum, 1, 64);
    rsum += __shfl_xor(rsum, 2, 64);
    if (rs != nullptr && l0 == 0 && (t & 3) == 0)
        rs[(size_t)(i0 + ra) * N + j] = rsum;

    __syncthreads();
#pragma unroll
    for (int m = 0; m < 4; ++m)
#pragma unroll
        for (int n = 0; n < 3; ++n)
#pragma unroll
            for (int r = 0; r < 4; ++r)
                sm.C[(m * 16 + fx * 4 + r) * 200 + wv * 48 + n * 16 + fr] =
                    f32_to_bf16(acc[m][n][r]);
    __syncthreads();
#pragma unroll
    for (int it = 0; it < 6; ++it) {
        const int cid = it * 256 + t;
        const int row = cid / 24;
        const int c   = cid % 24;
        *(uint4*)(e + (size_t)(i0 + row) * N2 + (size_t)j * N + l0 + c * 8) =
            *(const uint4*)&sm.C[row * 200 + c * 8];
    }
}

// ---------------------------------------------------------------------------
// k_eT: et[i][l][m] = e[i][m][l]
// ---------------------------------------------------------------------------
__global__ __launch_bounds__(256) void k_eT(const unsigned short* __restrict__ e,
                                            unsigned short* __restrict__ et) {
    __shared__ unsigned short tile[64][68];
    const int m0 = blockIdx.x * 64, l0 = blockIdx.y * 64;
    const size_t ib = (size_t)blockIdx.z * N2;
    const int t  = threadIdx.x;
    const int c4 = (t & 15) * 4, r = t >> 4;
#pragma unroll
    for (int p = 0; p < 4; ++p) {
        ushort4 v = *(const ushort4*)(e + ib + (size_t)(m0 + r + 16 * p) * N + l0 + c4);
        tile[c4 + 0][r + 16 * p] = v.x;
        tile[c4 + 1][r + 16 * p] = v.y;
        tile[c4 + 2][r + 16 * p] = v.z;
        tile[c4 + 3][r + 16 * p] = v.w;
    }
    __syncthreads();
#pragma unroll
    for (int p = 0; p < 4; ++p) {
        const int lr = r + 16 * p;
        ushort4 v = *(const ushort4*)&tile[lr][c4];
        *(ushort4*)(et + ib + (size_t)(l0 + lr) * N + m0 + c4) = v;
    }
}

// ---------------------------------------------------------------------------
// k_attn: one wave per row (i,j); rs precomputed by k_e2
// ---------------------------------------------------------------------------
template <bool HAVE_RS>
__global__ __launch_bounds__(256) void k_attn(const float* __restrict__ in,
                                              const float* __restrict__ w,
                                              const float* __restrict__ rs,
                                              unsigned short* __restrict__ attn) {
    const int row  = blockIdx.x * 4 + (threadIdx.x >> 6);
    const int lane = threadIdx.x & 63;
    const int jr   = row % N;

    const float2* wp = (const float2*)(w + (size_t)row * N);

    float2 wv[3];
    float rs_in = 0.f, rs_w = 0.f;
#pragma unroll
    for (int c = 0; c < 3; ++c) {
        wv[c] = wp[lane + 64 * c];
        rs_w += wv[c].x + wv[c].y;
    }
    if (HAVE_RS) {
#pragma unroll
        for (int s = 1; s < 64; s <<= 1) rs_w += __shfl_xor(rs_w, s, 64);
        rs_in = rs[row];
    } else {
        const float2* ip = (const float2*)(in + (size_t)row * N);
#pragma unroll
        for (int c = 0; c < 3; ++c) {
            float2 iv = ip[lane + 64 * c];
            rs_in += iv.x + iv.y;
        }
#pragma unroll
        for (int s = 1; s < 64; s <<= 1) {
            rs_in += __shfl_xor(rs_in, s, 64);
            rs_w  += __shfl_xor(rs_w, s, 64);
        }
    }
    const float scale = rs_in / (0.5f + rs_w);

    float2 q[3];
    float mx = -INFINITY;
#pragma unroll
    for (int c = 0; c < 3; ++c) {
        const int l = (lane + 64 * c) * 2;
        q[c].x = (l     <= jr) ? scale * wv[c].x : -INFINITY;
        q[c].y = (l + 1 <= jr) ? scale * wv[c].y : -INFINITY;
        mx = fmaxf(mx, fmaxf(q[c].x, q[c].y));
    }
#pragma unroll
    for (int s = 1; s < 64; s <<= 1) mx = fmaxf(mx, __shfl_xor(mx, s, 64));

    float2 p[3];
    float sum = 0.f;
#pragma unroll
    for (int c = 0; c < 3; ++c) {
        const int l = (lane + 64 * c) * 2;
        p[c].x = (l     <= jr) ? exp2f((q[c].x - mx) * 1.44269504f) : 0.f;
        p[c].y = (l + 1 <= jr) ? exp2f((q[c].y - mx) * 1.44269504f) : 0.f;
        sum += p[c].x + p[c].y;
    }
#pragma unroll
    for (int s = 1; s < 64; s <<= 1) sum += __shfl_xor(sum, s, 64);
    const float inv = 1.f / sum;
    unsigned int* ap = (unsigned int*)(attn + (size_t)row * N);
#pragma unroll
    for (int c = 0; c < 3; ++c)
        ap[lane + 64 * c] = pk2(p[c].x * inv, p[c].y * inv);
}

// ---------------------------------------------------------------------------
// k_av128: per i: out[j0..j0+127, l0..l0+127] = attn[i] @ et[i]^T
// BM=128, BN=128, BK=64, 4 waves (2x2, wave tile 64x64), all-gll staging,
// triangular K: nt = j0/64 + 2 tiles.
// ---------------------------------------------------------------------------
__global__ __launch_bounds__(256, 4) void k_av128(const unsigned short* __restrict__ attn,
                                                  const unsigned short* __restrict__ et,
                                                  float* __restrict__ out) {
    __shared__ union {
        struct { unsigned short A[128 * 64]; unsigned short B[128 * 64]; } s;
        float C[32 * 132];
    } sm;

    const int lin = blockIdx.x;               // 3456 = 8 * 432
    const int swz = (lin & 7) * 432 + (lin >> 3);
    const int i   = swz / 9;
    const int sub = swz % 9;
    const int j0  = (sub / 3) * 128;
    const int l0  = (sub % 3) * 128;
    const int nt  = (j0 >> 6) + 2;            // K tiles: 2 / 4 / 6

    const int t = threadIdx.x, lane = t & 63, wv = t >> 6;
    const int fr = lane & 15, fx = lane >> 4;
    const int wr = (wv >> 1) * 64;            // j-offset of wave tile
    const int wc = (wv & 1) * 64;             // l-offset of wave tile
    const int rb_off = lane >> 3;
    const int p8     = lane & 7;

    const unsigned short* Ag = attn + (size_t)i * N2 + (size_t)j0 * N;
    const unsigned short* Bg = et + (size_t)i * N2 + (size_t)l0 * N;

    f32x4 acc[4][4];
#pragma unroll
    for (int m = 0; m < 4; ++m)
#pragma unroll
        for (int n = 0; n < 4; ++n) acc[m][n] = (f32x4){0.f, 0.f, 0.f, 0.f};

    for (int tt = 0; tt < nt; ++tt) {
        const int k0 = tt * 64;
        __syncthreads();
        // A: 128 rows, wave stages rows [wv*32, wv*32+32), 4 ops x 8 rows
#pragma unroll
        for (int op = 0; op < 4; ++op) {
            const int rr = wv * 32 + op * 8 + rb_off;
            const int sc = p8 ^ (rr & 7);
            gll16(Ag + (size_t)rr * N + k0 + sc * 8,
                  sm.s.A + (wv * 32 + op * 8) * 64);
        }
        // B: 128 rows, same pattern
#pragma unroll
        for (int op = 0; op < 4; ++op) {
            const int rr = wv * 32 + op * 8 + rb_off;
            const int sc = p8 ^ (rr & 7);
            gll16(Bg + (size_t)rr * N + k0 + sc * 8,
                  sm.s.B + (wv * 32 + op * 8) * 64);
        }
        __syncthreads();
#pragma unroll
        for (int kk = 0; kk < 2; ++kk) {
            s16x8 af[4], bf[4];
#pragma unroll
            for (int m = 0; m < 4; ++m) {
                const int row = wr + m * 16 + fr;
                const int x   = (kk * 4 + fx) ^ (row & 7);
                af[m] = *(const s16x8*)(sm.s.A + row * 64 + x * 8);
            }
#pragma unroll
            for (int n = 0; n < 4; ++n) {
                const int row = wc + n * 16 + fr;
                const int x   = (kk * 4 + fx) ^ (row & 7);
                bf[n] = *(const s16x8*)(sm.s.B + row * 64 + x * 8);
            }
#pragma unroll
            for (int m = 0; m < 4; ++m)
#pragma unroll
                for (int n = 0; n < 4; ++n)
                    acc[m][n] = __builtin_amdgcn_mfma_f32_16x16x32_bf16(
                        af[m], bf[n], acc[m][n], 0, 0, 0);
        }
    }

    // epilogue: 4 phases of 32 fp32 rows [p*32, p*32+32)
    const int rq = fx * 4;
#pragma unroll
    for (int p = 0; p < 4; ++p) {
        __syncthreads();
        if ((wv >> 1) == (p >> 1)) {
            const int mbase = (p & 1) * 2;
#pragma unroll
            for (int mm = 0; mm < 2; ++mm)
#pragma unroll
                for (int n = 0; n < 4; ++n)
#pragma unroll
                    for (int r = 0; r < 4; ++r)
                        sm.C[(mm * 16 + rq + r) * 132 + wc + n * 16 + fr] =
                            acc[mbase + mm][n][r];
        }
        __syncthreads();
#pragma unroll
        for (int it = 0; it < 4; ++it) {
            const int cid = it * 256 + t;
            const int row = cid >> 5;
            const int c   = cid & 31;
            *(float4*)(out + (size_t)i * N2 + (size_t)(j0 + p * 32 + row) * N + l0 + c * 4) =
                *(const float4*)&sm.C[row * 132 + c * 4];
        }
    }
}

extern "C" void kernel_launch(void* const* d_in, const int* in_sizes, int n_in,
                              void* d_out, int out_size, void* d_ws, size_t ws_size,
                              hipStream_t stream) {
    const float* in = (const float*)d_in[0];
    const float* w  = (const float*)d_in[1];
    float* out      = (float*)d_out;

    unsigned short* r0 = (unsigned short*)d_ws;       // wt -> et
    unsigned short* r1 = (unsigned short*)d_ws + N3;  // e  -> attn
    const bool have_rs = ws_size >= 2 * N3 * sizeof(unsigned short) + (size_t)N2 * sizeof(float);
    float* rs = have_rs ? (float*)((unsigned short*)d_ws + 2 * N3) : nullptr;

    kT<<<dim3(N2 / 64, N / 64), 256, 0, stream>>>(w, r0);
    k_e2<<<dim3(4608), 256, 0, stream>>>(in, r0, r1, rs);
    k_eT<<<dim3(6, 6, N), 256, 0, stream>>>(r1, r0);
    if (have_rs)
        k_attn<true><<<dim3(N2 / 4), 256, 0, stream>>>(in, w, rs, r1);
    else
        k_attn<false><<<dim3(N2 / 4), 256, 0, stream>>>(in, w, nullptr, r1);
    k_av128<<<dim3(3456), 256, 0, stream>>>(r1, r0, out);
}